// Round 5
// baseline (186.366 us; speedup 1.0000x reference)
//
#include <hip/hip_runtime.h>

// STDP delta_w on MI355X, bf16-MFMA formulation (2-dispatch).
//   term1: dW1[o,p] = sum_k O[k,o]*TP[k,p], K = T*B = 1024  -> bf16 MFMA GEMM
//   term2: -coef[o]*W[o,p], coef[o] = sum_k O[k,o]*PO[k,o]  -> fp32 epilogue
//
// R11: GEMM re-tiled for CROSS-BLOCK overlap (the mechanism all prior
//   schedules lacked at 1 block/CU): 128x128 tile, 256 thr / 4 waves,
//   double-buffered LDS 64 KB -> 2 blocks/CU. Minimum-2-phase loop
//   (catalog T3 recipe): STAGE(t+1) -> buf^1, ds_read buf, 32 MFMA,
//   one __syncthreads per K-tile (vmcnt drain intentionally covered by
//   the co-resident block, m114 mechanism). Staging/read swizzle =
//   verbatim R6 mapping (verified twice, 0 bank conflicts). Epilogue:
//   nontemporal W loads + C stores. XCD-bijective swizzle (1024 blocks).
// Converter identical to R10 (passed).
//
// ws: AT bf16 [4096][1024] (8MB) | BT bf16 [4096][1024] (8MB) | coef f32[4096]

#define T_STEPS 64
#define B_SZ    16
#define PRE     4096
#define POST    4096
#define K_TOT   1024

typedef __attribute__((ext_vector_type(8))) unsigned short ushort8;
typedef __attribute__((ext_vector_type(8))) __bf16 bf16x8;
typedef __attribute__((ext_vector_type(4))) float floatx4;

__device__ __forceinline__ unsigned short f2bf(float f) {
    unsigned int u = __float_as_uint(f);
    u += 0x7fff + ((u >> 16) & 1);          // round-to-nearest-even
    return (unsigned short)(u >> 16);
}

__device__ __forceinline__ void glds16(const void* g, void* l) {
    __builtin_amdgcn_global_load_lds((const __attribute__((address_space(1))) void*)g,
                                     (__attribute__((address_space(3))) void*)l,
                                     16, 0, 0);
}

// ---------------------------------------------------------------------------
// Converter R10: grid = 512 blocks (matrix = blk>>8, p-chunk16 = blk&255),
// 256 thr; thread owns chain (b = tid>>4, p = tid&15) for all 64 t. (passed)
__global__ __launch_bounds__(256) void trace_convert(
        const float* __restrict__ in_spikes,
        const float* __restrict__ out_spikes,
        unsigned short* __restrict__ AT,
        unsigned short* __restrict__ BT,
        float* __restrict__ coef) {
    __shared__ unsigned short ot[128 * 17];  // [128 k][16 p + 1 pad], 4.25 KB
    __shared__ float cbuf[16 * 17];
    const int tid  = threadIdx.x;
    const bool isA = blockIdx.x >= 256;
    const int p0 = (blockIdx.x & 255) * 16;
    const float* src = isA ? out_spikes : in_spikes;
    unsigned short* dst = isA ? AT : BT;

    const int p = tid & 15;
    const int b = tid >> 4;
    const float* gbase = src + (size_t)b * PRE + p0 + p;

    const int pf = tid >> 4;                 // flush: p-row 0..15
    const int ch = tid & 15;                 // flush: 16-B chunk (8 k) 0..15
    unsigned short* dstf = &dst[(size_t)(p0 + pf) * K_TOT + ch * 8];

    float x[2][8];
    float st = 0.f, c0 = 0.f;

    #pragma unroll
    for (int tl = 0; tl < 8; ++tl) x[0][tl] = gbase[(size_t)tl * 65536];

    #pragma unroll
    for (int c = 0; c < 8; ++c) {
        if (c < 7) {
            #pragma unroll
            for (int tl = 0; tl < 8; ++tl)
                x[(c + 1) & 1][tl] = gbase[(size_t)((c + 1) * 8 + tl) * 65536];
        }
        #pragma unroll
        for (int tl = 0; tl < 8; ++tl) {
            const float xv = x[c & 1][tl];
            unsigned short ov;
            if (isA) {
                st = 0.5f * st + xv;         // po update
                c0 += xv * st;               // o * po
                ov = f2bf(xv);               // A stores raw o
            } else {
                st = fminf(fmaxf(0.5f * st + xv, 0.f), 1.f);
                ov = f2bf(st);               // B stores clipped trace
            }
            ot[(tl * 16 + b) * 17 + p] = ov;
        }
        asm volatile("s_waitcnt lgkmcnt(0)" ::: "memory");
        __builtin_amdgcn_s_barrier();
        __builtin_amdgcn_sched_barrier(0);

        ushort8 v;
        #pragma unroll
        for (int s = 0; s < 8; ++s) v[s] = ot[(ch * 8 + s) * 17 + pf];
        *(ushort8*)&dstf[c * 128] = v;

        asm volatile("s_waitcnt lgkmcnt(0)" ::: "memory");
        __builtin_amdgcn_s_barrier();
        __builtin_amdgcn_sched_barrier(0);
    }

    if (isA) {
        cbuf[b * 17 + p] = c0;
        asm volatile("s_waitcnt lgkmcnt(0)" ::: "memory");
        __builtin_amdgcn_s_barrier();
        if (tid < 16) {
            float s = 0.f;
            #pragma unroll
            for (int r = 0; r < 16; ++r) s += cbuf[r * 17 + tid];
            coef[p0 + tid] = s;
        }
    }
}

// ---------------------------------------------------------------------------
// R11 GEMM: 128x128 tile, BK=64, 4 waves, double-buffered LDS (64 KB ->
// 2 blocks/CU), one __syncthreads per K-tile. Staging map = verified R6.
#define BK 64

__global__ __launch_bounds__(256, 2) void stdp_gemm_mfma(
        const unsigned short* __restrict__ AT,   // [POST][K] bf16 bits
        const unsigned short* __restrict__ BT,   // [PRE][K]  bf16 bits
        const float* __restrict__ W,             // [POST][PRE]
        const float* __restrict__ coef,          // [POST]
        float* __restrict__ Cout) {              // [POST][PRE]
    __shared__ unsigned short As[2][128][BK];    // 2 x 16 KB
    __shared__ unsigned short Bs[2][128][BK];    // 2 x 16 KB
    const int tid  = threadIdx.x;
    const int lane = tid & 63;
    const int wave = tid >> 6;
    const int wm = (wave >> 1) * 64;
    const int wn = (wave & 1) * 64;

    // XCD-bijective swizzle: 1024 blocks = 8 XCD x 128; per XCD 4 m-panels x 32 n
    // (m-major within XCD -> A-row reuse stays in one L2).
    const int bid = blockIdx.x;
    const int f   = (bid & 7) * 128 + (bid >> 3);
    const int m0  = (f >> 5) * 128;
    const int n0  = (f & 31) * 128;

    floatx4 acc[4][4];
    #pragma unroll
    for (int i = 0; i < 4; ++i)
        #pragma unroll
        for (int j = 0; j < 4; ++j)
            acc[i][j] = (floatx4){0.f, 0.f, 0.f, 0.f};

    // Staging (verified R6): thread -> row srow = tid>>3 (+32 per instr),
    // LDS slot tid&7 receives global chunk (tid&7)^(row&7).
    const int srow = tid >> 3;                   // 0..31
    const int qg   = (tid & 7) ^ (srow & 7);
    const unsigned short* ga = &AT[(size_t)(m0 + srow) * K_TOT + qg * 8];
    const unsigned short* gb = &BT[(size_t)(n0 + srow) * K_TOT + qg * 8];

    const int rm = lane & 15;                    // fragment row (m or n)
    const int q  = lane >> 4;                    // k-quad within half
    const int sw = rm & 7;                       // read-side swizzle

    #define STAGE(t, buf)                                                      \
        do {                                                                   \
            char* laB_ = (char*)&As[buf][0][0] + wave * 1024;                  \
            char* lbB_ = (char*)&Bs[buf][0][0] + wave * 1024;                  \
            const unsigned short* ga_ = ga + (t) * BK;                         \
            const unsigned short* gb_ = gb + (t) * BK;                         \
            _Pragma("unroll")                                                  \
            for (int i_ = 0; i_ < 4; ++i_) {                                   \
                glds16(ga_ + (size_t)i_ * 32 * K_TOT, laB_ + i_ * 4096);       \
                glds16(gb_ + (size_t)i_ * 32 * K_TOT, lbB_ + i_ * 4096);       \
            }                                                                  \
        } while (0)

    STAGE(0, 0);
    __syncthreads();                             // drains vmcnt -> buf0 ready

    #pragma unroll
    for (int t = 0; t < K_TOT / BK; ++t) {
        const int buf = t & 1;
        if (t + 1 < K_TOT / BK) STAGE(t + 1, buf ^ 1);   // in flight during compute
        #pragma unroll
        for (int h = 0; h < 2; ++h) {            // two 32-k halves
            const int ks = ((h * 4 + q) ^ sw) * 8;
            bf16x8 af[4], bv[4];
            #pragma unroll
            for (int i = 0; i < 4; ++i) {
                af[i] = *(const bf16x8*)&As[buf][wm + i * 16 + rm][ks];
                bv[i] = *(const bf16x8*)&Bs[buf][wn + i * 16 + rm][ks];
            }
            __builtin_amdgcn_s_setprio(1);
            #pragma unroll
            for (int mi = 0; mi < 4; ++mi)
                #pragma unroll
                for (int ni = 0; ni < 4; ++ni)
                    acc[mi][ni] = __builtin_amdgcn_mfma_f32_16x16x32_bf16(
                        af[mi], bv[ni], acc[mi][ni], 0, 0, 0);
            __builtin_amdgcn_s_setprio(0);
        }
        __syncthreads();                         // drain covered by 2nd block/CU
    }
    #undef STAGE

    // Epilogue: C = acc - coef[o]*W. C/D layout: col=lane&15, row=quad*4+reg.
    // Nontemporal: W never reused by this kernel, C never read.
    const int colp = n0 + wn + rm;
    const int rowb = m0 + wm + (lane >> 4) * 4;
    #pragma unroll
    for (int mi = 0; mi < 4; ++mi) {
        #pragma unroll
        for (int r = 0; r < 4; ++r) {
            const int o = rowb + mi * 16 + r;
            const float cf = coef[o];
            const float* wr = &W[(size_t)o * PRE];
            float* cr = &Cout[(size_t)o * PRE];
            #pragma unroll
            for (int ni = 0; ni < 4; ++ni) {
                const int p = colp + ni * 16;
                const float wv = __builtin_nontemporal_load(&wr[p]);
                __builtin_nontemporal_store(acc[mi][ni][r] - cf * wv, &cr[p]);
            }
        }
    }
}

// ---------------------------------------------------------------------------
extern "C" void kernel_launch(void* const* d_in, const int* in_sizes, int n_in,
                              void* d_out, int out_size, void* d_ws, size_t ws_size,
                              hipStream_t stream) {
    const float* in_spikes  = (const float*)d_in[0];
    const float* out_spikes = (const float*)d_in[1];
    const float* weight     = (const float*)d_in[2];
    float* out = (float*)d_out;

    unsigned short* AT = (unsigned short*)d_ws;                 // 8 MB
    unsigned short* BT = AT + (size_t)POST * K_TOT;             // 8 MB
    float* coef = (float*)(BT + (size_t)PRE * K_TOT);           // 16 KB

    trace_convert<<<512, 256, 0, stream>>>(in_spikes, out_spikes, AT, BT, coef);

    stdp_gemm_mfma<<<1024, 256, 0, stream>>>(AT, BT, weight, coef, out);
}